// Round 4
// baseline (105.753 us; speedup 1.0000x reference)
//
#include <hip/hip_runtime.h>

#define HW 361
#define S_OFF 8192                      // S[b][c][s], s-stride 128 : 128*32*128 floats
#define P_OFF (8192 + 128*32*128)       // P[b][o][s], s-stride 128 : 128*64*128 floats

// ---------------- K1: fold weights ----------------
// wsf[0:2048)    wlT[c][o]
// wsf[2048:4096) wdT[c][o]
// wsf[4096:6144) w2T[c][o] = -2*(wl+wd)
__global__ __launch_bounds__(256) void prep_w(const float* __restrict__ weight,
                                              float* __restrict__ wsf) {
  int t = blockIdx.x * 256 + threadIdx.x;
  if (t >= 2048) return;
  int o = t >> 5, c = t & 31;
  const float* wp = weight + (size_t)(o * 32 + c) * 36;
  float sl = 0.f, sd = 0.f;
#pragma unroll
  for (int r = 0; r < 18; ++r) { sl += wp[r]; sd += wp[18 + r]; }
  wsf[c * 64 + o] = sl;
  wsf[2048 + c * 64 + o] = sd;
  wsf[4096 + c * 64 + o] = -2.f * (sl + sd);
}

// ---------------- K2a: line sums ----------------
// grid 512 = 128 b x 4 cgroups; S slots: row h@s=h, col w@20+w, diag k@40+k (k=h-w+18),
// anti k@80+k (k=h+w). Slots 19,39,77..79,117..127 unused.
__global__ __launch_bounds__(256) void sums_k(const float* __restrict__ x,
                                              float* __restrict__ wsf) {
  __shared__ float sx[8 * 364];
  const int b = blockIdx.x >> 2, cg = blockIdx.x & 3;
  const int tid = threadIdx.x;
  const float* xb = x + (size_t)b * (32 * HW) + (size_t)cg * 8 * HW;

  // stage 8 planes; per-plane so LDS f4 writes stay 16B-aligned
  for (int u = tid; u < 728; u += 256) {
    int c = u / 91, j = u - c * 91;
    if (j < 90) {
      float4 v = *reinterpret_cast<const float4*>(xb + c * HW + 4 * j);  // 4B-aligned ok
      *reinterpret_cast<float4*>(sx + c * 364 + 4 * j) = v;
    } else {
      sx[c * 364 + 360] = xb[c * HW + 360];
    }
  }
  __syncthreads();

  float* wsS = wsf + S_OFF + ((size_t)b * 32 + cg * 8) * 128;
  for (int it = tid; it < 1024; it += 256) {
    int c = it >> 7, s = it & 127;
    const float* p = sx + c * 364;
    float sum = 0.f;
    bool valid = true;
    if (s < 19) {
      const float* q = p + s * 19;
#pragma unroll
      for (int w = 0; w < 19; ++w) sum += q[w];
    } else if (s >= 20 && s < 39) {
      const float* q = p + (s - 20);
#pragma unroll
      for (int h = 0; h < 19; ++h) sum += q[h * 19];
    } else if (s >= 40 && s < 77) {
      int k = s - 40;
      int hmin = k > 18 ? k - 18 : 0, hmax = k < 18 ? k : 18;
      const float* q = p + (18 - k);
      float acc = 0.f;
      for (int h = hmin; h <= hmax; ++h) acc += q[h * 20];
      sum = acc;
    } else if (s >= 80 && s < 117) {
      int k = s - 80;
      int hmin = k > 18 ? k - 18 : 0, hmax = k < 18 ? k : 18;
      const float* q = p + k;
      float acc = 0.f;
      for (int h = hmin; h <= hmax; ++h) acc += q[h * 18];
      sum = acc;
    } else {
      valid = false;
    }
    if (valid) wsS[c * 128 + s] = sum;
  }
}

// ---------------- K2b: project sums onto outputs ----------------
// grid 256 = 128 b x 2 s-halves. P[b][o][s] = sum_c wT[c][o] * S[b][c][s]
__global__ __launch_bounds__(256) void proj_k(float* __restrict__ wsf) {
  __shared__ float sS[32 * 64];
  __shared__ float sWL[32 * 64];
  __shared__ float sWD[32 * 64];
  const int b = blockIdx.x >> 1, sh = blockIdx.x & 1;
  const int sbase = sh * 64;
  const int tid = threadIdx.x;

  const float4* w4 = reinterpret_cast<const float4*>(wsf);
  for (int i = tid; i < 1024; i += 256) {
    float4 v = w4[i];
    if (i < 512) reinterpret_cast<float4*>(sWL)[i] = v;
    else reinterpret_cast<float4*>(sWD)[i - 512] = v;
  }
  const float* Sb = wsf + S_OFF + (size_t)b * 32 * 128 + sbase;
  for (int i = tid; i < 512; i += 256) {
    int c = i >> 4, j = i & 15;
    reinterpret_cast<float4*>(sS)[c * 16 + j] =
        *reinterpret_cast<const float4*>(Sb + c * 128 + 4 * j);
  }
  __syncthreads();

  const int ot = tid >> 4, st = tid & 15;
  const int o0 = ot * 4, s0 = st * 4;
  const float* wT = (sbase + s0 < 40) ? sWL : sWD;
  float a[4][4] = {};
#pragma unroll 4
  for (int c = 0; c < 32; ++c) {
    float4 wv = *reinterpret_cast<const float4*>(wT + c * 64 + o0);
    float4 sv = *reinterpret_cast<const float4*>(sS + c * 64 + s0);
    float wr[4] = {wv.x, wv.y, wv.z, wv.w};
    float sr[4] = {sv.x, sv.y, sv.z, sv.w};
#pragma unroll
    for (int i = 0; i < 4; ++i)
#pragma unroll
      for (int j = 0; j < 4; ++j) a[i][j] = fmaf(wr[i], sr[j], a[i][j]);
  }
  float* Pb = wsf + P_OFF + (size_t)b * 64 * 128 + sbase;
#pragma unroll
  for (int i = 0; i < 4; ++i) {
    float4 v = {a[i][0], a[i][1], a[i][2], a[i][3]};
    *reinterpret_cast<float4*>(Pb + (o0 + i) * 128 + s0) = v;
  }
}

// ---------------- K3: main GEMM + table epilogue ----------------
// 1 reg-tile (4o x 4w, one board row) per thread; no LDS.
// units per batch: 16 og * 19 h * 5 wt = 1520; total 194560 threads = 760 blocks.
__global__ __launch_bounds__(256) void main_k(const float* __restrict__ x,
                                              const float* __restrict__ bias,
                                              const float* __restrict__ wsf,
                                              float* __restrict__ out) {
  const int tg = blockIdx.x * 256 + threadIdx.x;
  const int b = tg / 1520;
  int rem = tg - b * 1520;
  const int og = rem / 95;
  int rem2 = rem - og * 95;
  const int h = rem2 / 5;
  const int wt = rem2 - h * 5;
  const int w0 = wt * 4;
  const int nw = (wt == 4) ? 3 : 4;
  const int sel = (wt == 4) ? 1 : 0;     // shifted load to stay in-plane
  const int o0 = og * 4;

  const float* xb = x + (size_t)b * (32 * HW);
  const float* w2 = wsf + 4096;
  const int xoff = h * 19 + w0 - sel;

  float acc[4][4] = {};
#pragma unroll 4
  for (int c = 0; c < 32; ++c) {
    float4 xv = *reinterpret_cast<const float4*>(xb + c * HW + xoff);
    float vv[4] = {xv.x, xv.y, xv.z, xv.w};
    float xr[4];
    xr[0] = vv[sel];
    xr[1] = vv[1 + sel];
    xr[2] = vv[2 + sel];
    xr[3] = sel ? 0.f : vv[3];
    float4 wv = *reinterpret_cast<const float4*>(w2 + c * 64 + o0);
    float wr[4] = {wv.x, wv.y, wv.z, wv.w};
#pragma unroll
    for (int i = 0; i < 4; ++i)
#pragma unroll
      for (int j = 0; j < 4; ++j) acc[i][j] = fmaf(wr[i], xr[j], acc[i][j]);
  }

  const float* Pb = wsf + P_OFF + ((size_t)b * 64 + o0) * 128;
  float4 bv = *reinterpret_cast<const float4*>(bias + o0);
  float br[4] = {bv.x, bv.y, bv.z, bv.w};

#pragma unroll
  for (int i = 0; i < 4; ++i) {
    const float* pp = Pb + i * 128;
    float A = pp[h];                                                   // row table
    float4 Bv = *reinterpret_cast<const float4*>(pp + 20 + w0);        // col table
    float4 Dv = *reinterpret_cast<const float4*>(pp + 55 + h - w0);    // diag (reversed)
    float4 Gv = *reinterpret_cast<const float4*>(pp + 80 + h + w0);    // anti-diag
    float Br[4] = {Bv.x, Bv.y, Bv.z, Bv.w};
    float Dr[4] = {Dv.x, Dv.y, Dv.z, Dv.w};
    float Gr[4] = {Gv.x, Gv.y, Gv.z, Gv.w};
    float* op = out + ((size_t)b * 64 + o0 + i) * HW + h * 19 + w0;
    float res[4];
#pragma unroll
    for (int j = 0; j < 4; ++j)
      res[j] = acc[i][j] + A + Br[j] + Dr[3 - j] + Gr[j] + br[i];
    if (nw == 4) {
      float4 ov = {res[0], res[1], res[2], res[3]};
      *reinterpret_cast<float4*>(op) = ov;
    } else {
      op[0] = res[0]; op[1] = res[1]; op[2] = res[2];
    }
  }
}

extern "C" void kernel_launch(void* const* d_in, const int* in_sizes, int n_in,
                              void* d_out, int out_size, void* d_ws, size_t ws_size,
                              hipStream_t stream) {
  const float* x      = (const float*)d_in[0];
  const float* weight = (const float*)d_in[1];
  const float* bias   = (const float*)d_in[2];
  float* out = (float*)d_out;
  float* wsf = (float*)d_ws;

  prep_w<<<8, 256, 0, stream>>>(weight, wsf);
  sums_k<<<512, 256, 0, stream>>>(x, wsf);
  proj_k<<<256, 256, 0, stream>>>(wsf);
  main_k<<<760, 256, 0, stream>>>(x, bias, wsf, out);
}

// Round 6
// 84.480 us; speedup vs baseline: 1.2518x; 1.2518x over previous
//
#include <hip/hip_runtime.h>

#define HW 361
// LDS float offsets
#define SX   0        // [32][380]: 19 rows padded to 20 floats, col 19 = 0
#define SXs  380
#define SS   12160    // [32][120]: rows@0-18, cols@20-39(col19sum=0), diag@40-76, anti@80-116
#define SSs  120
#define SP   16000    // [32][120]: projected tables per local output o'
#define SPs  120
#define SWL  19840    // [32][32] line-weight^T (c-major)
#define SWD  20864    // [32][32] diag-weight^T
#define SW2  21888    // [32][32] -2*(WL+WD)^T
#define SB   22912    // [32] bias
#define LDSF 22944    // 91,776 B -> 1 block/CU, 8 waves

__device__ __forceinline__ float4 ld4(const float* p) {
  return *reinterpret_cast<const float4*>(p);
}
__device__ __forceinline__ void st4(float* p, float4 v) {
  *reinterpret_cast<float4*>(p) = v;
}

__global__ __launch_bounds__(512) void fused_k(
    const float* __restrict__ x, const float* __restrict__ weight,
    const float* __restrict__ bias, float* __restrict__ out) {
  __shared__ float sm[LDSF];
  const int tid = threadIdx.x;
  const int b = blockIdx.x >> 1;
  const int obase = (blockIdx.x & 1) << 5;     // local 32-output half
  const float* xb = x + (size_t)b * (32 * HW);

  // ---- P0a: fold weights into LDS (this block's 32 outputs only) ----
  for (int p = tid; p < 1024; p += 512) {
    int o = p >> 5, c = p & 31;
    const float* wp = weight + (size_t)((obase + o) * 32 + c) * 36;
    float sl = 0.f, sd = 0.f;
#pragma unroll
    for (int r = 0; r < 18; ++r) { sl += wp[r]; sd += wp[18 + r]; }
    sm[SWL + c * 32 + o] = sl;
    sm[SWD + c * 32 + o] = sd;
    sm[SW2 + c * 32 + o] = -2.f * (sl + sd);
  }
  if (tid < 32) sm[SB + tid] = bias[obase + tid];
  // zero the unused S slots so proj reads are defined
  if (tid >= 64 && tid < 96) {
    int c = tid - 64;
    float* q = sm + SS + c * SSs;
    q[19] = 0.f; q[77] = 0.f; q[78] = 0.f; q[79] = 0.f;
    q[117] = 0.f; q[118] = 0.f; q[119] = 0.f;
  }
  // ---- P0b: stage x, rows padded to 20 (col 19 = 0), all f4 LDS-aligned ----
  for (int it = tid; it < 3040; it += 512) {
    int c = it / 95, rem = it - c * 95;
    int h = rem / 5, g = rem - h * 5;
    const float* src = xb + c * HW + h * 19 + g * 4;
    float* dst = sm + SX + c * SXs + h * 20 + g * 4;
    if (g < 4) {
      st4(dst, ld4(src));                 // global f4 (4B-aligned ok)
    } else {
      float4 v = {src[0], src[1], src[2], 0.f};   // tail: 3 scalars + zero pad
      st4(dst, v);
    }
  }
  __syncthreads();

  // ---- P1: line sums ----
  for (int it = tid; it < 608; it += 512) {        // rows (pad col contributes 0)
    int c = it / 19, h = it - c * 19;
    const float* p = sm + SX + c * SXs + h * 20;
    float4 a = ld4(p), b4 = ld4(p + 4), c4 = ld4(p + 8), d4 = ld4(p + 12), e4 = ld4(p + 16);
    sm[SS + c * SSs + h] =
        ((a.x + a.y) + (a.z + a.w)) + ((b4.x + b4.y) + (b4.z + b4.w)) +
        ((c4.x + c4.y) + (c4.z + c4.w)) + ((d4.x + d4.y) + (d4.z + d4.w)) +
        ((e4.x + e4.y) + (e4.z + e4.w));
  }
  for (int it = tid; it < 160; it += 512) {        // cols, 4 at a time via f4
    int c = it / 5, g = it - c * 5;
    const float* p = sm + SX + c * SXs + g * 4;
    float ax = 0.f, ay = 0.f, az = 0.f, aw = 0.f;
#pragma unroll
    for (int h = 0; h < 19; ++h) {
      float4 v = ld4(p + h * 20);
      ax += v.x; ay += v.y; az += v.z; aw += v.w;
    }
    float* q = sm + SS + c * SSs + 20 + g * 4;
    q[0] = ax; q[1] = ay; q[2] = az; q[3] = aw;    // slot 39 = pad-col sum = 0
  }
  for (int it = tid; it < 1184; it += 512) {       // main diag k=h-w+18: addr h*21+(18-k)
    int c = it / 37, k = it - c * 37;
    int hmin = k > 18 ? k - 18 : 0, hmax = k < 18 ? k : 18;
    const float* p = sm + SX + c * SXs + (18 - k);
    float s = 0.f;
    for (int h = hmin; h <= hmax; ++h) s += p[h * 21];
    sm[SS + c * SSs + 40 + k] = s;
  }
  for (int it = tid; it < 1184; it += 512) {       // anti diag k=h+w: addr h*19+k
    int c = it / 37, k = it - c * 37;
    int hmin = k > 18 ? k - 18 : 0, hmax = k < 18 ? k : 18;
    const float* p = sm + SX + c * SXs + k;
    float s = 0.f;
    for (int h = hmin; h <= hmax; ++h) s += p[h * 19];
    sm[SS + c * SSs + 80 + k] = s;
  }
  __syncthreads();

  // ---- P2: project sums onto outputs: P[o'][s] = sum_c wT[c][o']*S[c][s] ----
  if (tid < 240) {
    int ot = tid / 30, st = tid - ot * 30;
    int o0 = ot * 4, s0 = st * 4;
    const float* wT = sm + (s0 < 40 ? SWL : SWD);
    float a[4][4] = {};
#pragma unroll 8
    for (int c = 0; c < 32; ++c) {
      float4 wv = ld4(wT + c * 32 + o0);
      float4 sv = ld4(sm + SS + c * SSs + s0);
      float wr[4] = {wv.x, wv.y, wv.z, wv.w};
      float sr[4] = {sv.x, sv.y, sv.z, sv.w};
#pragma unroll
      for (int i = 0; i < 4; ++i)
#pragma unroll
        for (int j = 0; j < 4; ++j) a[i][j] = fmaf(wr[i], sr[j], a[i][j]);
    }
#pragma unroll
    for (int i = 0; i < 4; ++i) {
      float4 v = {a[i][0], a[i][1], a[i][2], a[i][3]};
      st4(sm + SP + (o0 + i) * SPs + s0, v);
    }
  }
  __syncthreads();

  // ---- P3: main GEMM (8o x 8w reg tiles) + table epilogue + store ----
  // units wg-major: wg 0,1 (8-wide) = 152 units, wg 2 (cols 16-18, 4-wide+pad) = 76
  if (tid < 228) {
    int wg, r;
    if (tid < 152) { wg = tid / 76; r = tid - wg * 76; }
    else           { wg = 2;        r = tid - 152; }
    const int og = r / 19, h = r - og * 19;
    const int o0 = og * 8;
    const size_t outbase = ((size_t)(b * 64 + obase + o0)) * HW + h * 19;

    if (wg < 2) {
      const int w0 = wg * 8;
      float acc[8][8] = {};
#pragma unroll 4
      for (int c = 0; c < 32; ++c) {
        float4 xa = ld4(sm + SX + c * SXs + h * 20 + w0);
        float4 xc = ld4(sm + SX + c * SXs + h * 20 + w0 + 4);
        float4 wa = ld4(sm + SW2 + c * 32 + o0);
        float4 wb = ld4(sm + SW2 + c * 32 + o0 + 4);
        float xr[8] = {xa.x, xa.y, xa.z, xa.w, xc.x, xc.y, xc.z, xc.w};
        float wr[8] = {wa.x, wa.y, wa.z, wa.w, wb.x, wb.y, wb.z, wb.w};
#pragma unroll
        for (int i = 0; i < 8; ++i)
#pragma unroll
          for (int j = 0; j < 8; ++j) acc[i][j] = fmaf(wr[i], xr[j], acc[i][j]);
      }
#pragma unroll
      for (int i = 0; i < 8; ++i) {
        const float* pp = sm + SP + (o0 + i) * SPs;
        float A = pp[h] + sm[SB + o0 + i];
        float4 B0 = ld4(pp + 20 + w0);
        float4 B1 = ld4(pp + 24 + w0);
        float Br[8] = {B0.x, B0.y, B0.z, B0.w, B1.x, B1.y, B1.z, B1.w};
        float res[8];
#pragma unroll
        for (int j = 0; j < 8; ++j) {
          float D = pp[58 + h - w0 - j];    // diag slot 40+(h-w+18)
          float G = pp[80 + h + w0 + j];    // anti slot 80+(h+w)
          res[j] = acc[i][j] + A + Br[j] + D + G;
        }
        float* op = out + outbase + (size_t)i * HW + w0;
        float4 r0 = {res[0], res[1], res[2], res[3]};
        float4 r1 = {res[4], res[5], res[6], res[7]};
        st4(op, r0);
        st4(op + 4, r1);
      }
    } else {
      float acc[8][4] = {};
#pragma unroll 4
      for (int c = 0; c < 32; ++c) {
        float4 xa = ld4(sm + SX + c * SXs + h * 20 + 16);  // cols 16..18 + pad0
        float4 wa = ld4(sm + SW2 + c * 32 + o0);
        float4 wb = ld4(sm + SW2 + c * 32 + o0 + 4);
        float xr[4] = {xa.x, xa.y, xa.z, xa.w};
        float wr[8] = {wa.x, wa.y, wa.z, wa.w, wb.x, wb.y, wb.z, wb.w};
#pragma unroll
        for (int i = 0; i < 8; ++i)
#pragma unroll
          for (int j = 0; j < 4; ++j) acc[i][j] = fmaf(wr[i], xr[j], acc[i][j]);
      }
#pragma unroll
      for (int i = 0; i < 8; ++i) {
        const float* pp = sm + SP + (o0 + i) * SPs;
        float A = pp[h] + sm[SB + o0 + i];
        float res[3];
#pragma unroll
        for (int j = 0; j < 3; ++j) {
          float D = pp[58 + h - 16 - j];
          float G = pp[80 + h + 16 + j];
          res[j] = acc[i][j] + A + pp[36 + j] + D + G;   // col slots 20+16+j
        }
        float* op = out + outbase + (size_t)i * HW + 16;
        op[0] = res[0]; op[1] = res[1]; op[2] = res[2];
      }
    }
  }
}

extern "C" void kernel_launch(void* const* d_in, const int* in_sizes, int n_in,
                              void* d_out, int out_size, void* d_ws, size_t ws_size,
                              hipStream_t stream) {
  const float* x      = (const float*)d_in[0];
  const float* weight = (const float*)d_in[1];
  const float* bias   = (const float*)d_in[2];
  // d_in[3]/d_in[4] (flat_index/valid_mask) encode full-board rays -> closed form, unused
  float* out = (float*)d_out;
  (void)d_ws; (void)ws_size;

  fused_k<<<256, 512, 0, stream>>>(x, weight, bias, out);
}